// Round 7
// baseline (849.503 us; speedup 1.0000x reference)
//
#include <hip/hip_runtime.h>

#define H 50
#define B_TOT 1024
#define S_TOT 2048

static __device__ __forceinline__ float fast_rcp(float x) {
#if __has_builtin(__builtin_amdgcn_rcpf)
    return __builtin_amdgcn_rcpf(x);
#else
    return 1.0f / x;
#endif
}

// tanh(x) = 1 - 2/(exp(2x)+1); inf-safe at both ends.
static __device__ __forceinline__ float fast_tanh(float x) {
    return fmaf(-2.0f, fast_rcp(__expf(2.0f * x) + 1.0f), 1.0f);
}

// pp[b][j] = sum_k dps[b][k] * W_prev[j][k]
__global__ __launch_bounds__(256) void pp_kernel(const float* __restrict__ dps,
                                                 const float* __restrict__ Wp,
                                                 float* __restrict__ pp) {
    int tid = blockIdx.x * 256 + threadIdx.x;      // B*H = 51200 = 200 blocks exactly
    int b = tid / H, j = tid - b * H;
    const float* dr = dps + b * H;
    const float* wr = Wp + j * H;
    float a0 = 0.f, a1 = 0.f, a2 = 0.f, a3 = 0.f;
#pragma unroll
    for (int k = 0; k < 48; k += 4) {
        a0 = fmaf(dr[k + 0], wr[k + 0], a0);
        a1 = fmaf(dr[k + 1], wr[k + 1], a1);
        a2 = fmaf(dr[k + 2], wr[k + 2], a2);
        a3 = fmaf(dr[k + 3], wr[k + 3], a3);
    }
    a0 = fmaf(dr[48], wr[48], a0);
    a1 = fmaf(dr[49], wr[49], a1);
    pp[tid] = (a0 + a1) + (a2 + a3);
}

// One thread owns one b for a chunk of SC s-values. No max-subtraction needed:
// |score| <= sum|W_score| ~= 7, so exp() is overflow-safe in fp32 and split-S
// partials combine as plain sums (no online-max rescale).
__global__ __launch_bounds__(256, 2) void attn_main(const float* __restrict__ enc,
                                                    const int* __restrict__ mask,
                                                    const float* __restrict__ Wenc,
                                                    const float* __restrict__ Wsc,
                                                    const float* __restrict__ pp,
                                                    float* __restrict__ pl,
                                                    float* __restrict__ pctx,
                                                    int SC) {
    const int c = blockIdx.x;
    const int b = blockIdx.y * 256 + threadIdx.x;
    const int s0 = c * SC;

    float ctx[H];
#pragma unroll
    for (int h = 0; h < H; ++h) ctx[h] = 0.f;
    float lsum = 0.f;

    // Hoist proj_prev row (loop-invariant across s) into registers.
    float ppr[H];
    {
        const float* pr = pp + b * H;
#pragma unroll
        for (int j = 0; j < H; j += 2) {
            float2 v = *reinterpret_cast<const float2*>(pr + j);
            ppr[j] = v.x;
            ppr[j + 1] = v.y;
        }
    }

    const int* mrow = mask + (size_t)b * S_TOT;

    for (int si = 0; si < SC; ++si) {
        const int s = s0 + si;
        // Row base offset = (s*1024 + b)*200 bytes -> always 8B-aligned.
        const float* er = enc + ((size_t)s * B_TOT + b) * H;

        float e[H];
#pragma unroll
        for (int q = 0; q < H; q += 2) {
            float2 v = *reinterpret_cast<const float2*>(er + q);
            e[q] = v.x;
            e[q + 1] = v.y;
        }

        float score = 0.f;
        for (int j = 0; j < H; ++j) {              // j uniform: Wenc/Wsc -> scalar loads
            const float* wr = Wenc + j * H;
            float a0 = ppr[j], a1 = 0.f, a2 = 0.f, a3 = 0.f;
#pragma unroll
            for (int k = 0; k < 48; k += 4) {
                a0 = fmaf(wr[k + 0], e[k + 0], a0);
                a1 = fmaf(wr[k + 1], e[k + 1], a1);
                a2 = fmaf(wr[k + 2], e[k + 2], a2);
                a3 = fmaf(wr[k + 3], e[k + 3], a3);
            }
            a0 = fmaf(wr[48], e[48], a0);
            a1 = fmaf(wr[49], e[49], a1);
            float acc = (a0 + a1) + (a2 + a3);
            score = fmaf(fast_tanh(acc), Wsc[j], score);
        }

        const float p = (mrow[s] != 0) ? __expf(score) : 0.0f;
        lsum += p;
#pragma unroll
        for (int h = 0; h < H; ++h) ctx[h] = fmaf(p, e[h], ctx[h]);
    }

    pl[c * B_TOT + b] = lsum;
    float* po = pctx + ((size_t)c * B_TOT + b) * H;
#pragma unroll
    for (int h = 0; h < H; ++h) po[h] = ctx[h];
}

// out[b][h] = sum_c pctx[c][b][h] / sum_c pl[c][b]
__global__ __launch_bounds__(256) void combine_kernel(const float* __restrict__ pl,
                                                      const float* __restrict__ pctx,
                                                      float* __restrict__ out,
                                                      int NC) {
    int tid = blockIdx.x * 256 + threadIdx.x;      // b*H + h, coalesced over pctx
    int b = tid / H;
    float csum = 0.f, lsum = 0.f;
    for (int c = 0; c < NC; ++c) {
        csum += pctx[(size_t)c * (B_TOT * H) + tid];
        lsum += pl[c * B_TOT + b];
    }
    out[tid] = csum / lsum;
}

extern "C" void kernel_launch(void* const* d_in, const int* in_sizes, int n_in,
                              void* d_out, int out_size, void* d_ws, size_t ws_size,
                              hipStream_t stream) {
    const float* dps  = (const float*)d_in[0];
    const float* enc  = (const float*)d_in[1];
    const int*   mask = (const int*)d_in[2];
    const float* Wp   = (const float*)d_in[3];
    const float* We   = (const float*)d_in[4];
    const float* Wsc  = (const float*)d_in[5];
    float* out = (float*)d_out;
    float* ws  = (float*)d_ws;

    // Prefer 256 S-chunks (SC=8) for load-balance granularity; halve until the
    // partial buffers fit the provided workspace.
    int NC = 256;
    while (NC > 1 &&
           (size_t)(B_TOT * H + (size_t)NC * B_TOT * (H + 1)) * sizeof(float) > ws_size)
        NC >>= 1;
    const int SC = S_TOT / NC;

    float* pp   = ws;
    float* pl   = ws + B_TOT * H;
    float* pctx = pl + (size_t)NC * B_TOT;

    hipLaunchKernelGGL(pp_kernel, dim3((B_TOT * H) / 256), dim3(256), 0, stream,
                       dps, Wp, pp);
    hipLaunchKernelGGL(attn_main, dim3(NC, B_TOT / 256), dim3(256), 0, stream,
                       enc, mask, We, Wsc, pp, pl, pctx, SC);
    hipLaunchKernelGGL(combine_kernel, dim3((B_TOT * H) / 256), dim3(256), 0, stream,
                       pl, pctx, out, NC);
}